// Round 3
// baseline (1308.862 us; speedup 1.0000x reference)
//
#include <hip/hip_runtime.h>

#define NN 100000
#define NE 3200000
#define NF 512
#define ND 64
#define NC 10

// workspace layout (float elements)
#define OFF_ACC   0            // NN*ND fp32 accumulator for propagation
#define OFF_H     6400000      // NN*ND transformed features h = x @ (W1*M1)
#define OFF_DEG   12800000     // NN   degree, overwritten in-place by deg^-1/2
#define OFF_W1    12900000     // NF*ND = 32768  Weff1 = W1*M1
#define OFF_W2    12932768     // ND*NC = 640    Weff2 = W2*M2
// total = 12,933,408 floats = 51,733,632 bytes of d_ws

// Zero acc, deg=1 (self-loop weight), masked weights.
__global__ __launch_bounds__(256) void prep_kernel(
    const float* __restrict__ W1, const float* __restrict__ M1,
    const float* __restrict__ W2, const float* __restrict__ M2,
    float* __restrict__ ws) {
  const int i = blockIdx.x * 256 + threadIdx.x;   // grid covers exactly NN*ND
  ws[OFF_ACC + i] = 0.0f;
  if (i < NN) ws[OFF_DEG + i] = 1.0f;
  if (i < NF * ND) ws[OFF_W1 + i] = W1[i] * M1[i];
  if (i < ND * NC) ws[OFF_W2 + i] = W2[i] * M2[i];
}

// deg[dst] += w  (in-degree; self-loop "+1" already in init)
__global__ __launch_bounds__(256) void deg_kernel(
    const int* __restrict__ dst, const float* __restrict__ ew,
    float* __restrict__ deg) {
  const int i = blockIdx.x * 256 + threadIdx.x;   // grid covers exactly NE
  atomicAdd(&deg[dst[i]], ew[i]);
}

// deg -> deg^{-1/2} in place (deg >= 1 from the self-loop)
__global__ __launch_bounds__(256) void dis_kernel(float* __restrict__ deg) {
  const int i = blockIdx.x * 256 + threadIdx.x;
  if (i < NN) {
    const float d = deg[i];
    deg[i] = d > 0.0f ? 1.0f / sqrtf(d) : 0.0f;
  }
}

// h[n][d] = sum_k x[n][k] * Weff1[k][d].  16 nodes per block staged in LDS
// (32 KB); thread (d = tid&63, g = tid>>6) accumulates 4 nodes.
__global__ __launch_bounds__(256) void gemm1_kernel(
    const float* __restrict__ x, const float* __restrict__ w,
    float* __restrict__ h) {
  __shared__ __align__(16) float xs[16 * NF];   // 32 KB
  const float4* xg = (const float4*)(x + (size_t)blockIdx.x * (16 * NF));
  float4* xl = (float4*)xs;
#pragma unroll
  for (int i = 0; i < 8; ++i) xl[threadIdx.x + 256 * i] = xg[threadIdx.x + 256 * i];
  __syncthreads();
  const int d = threadIdx.x & 63;
  const int g = threadIdx.x >> 6;   // 0..3
  float acc[4];
#pragma unroll
  for (int j = 0; j < 4; ++j) acc[j] = 0.0f;
  for (int k = 0; k < NF; k += 8) {
    float wv[8];
#pragma unroll
    for (int kk = 0; kk < 8; ++kk) wv[kk] = w[(k + kk) * ND + d];  // coalesced
#pragma unroll
    for (int j = 0; j < 4; ++j) {
      const int n = g * 4 + j;
      float4 a0 = *(const float4*)(&xs[n * NF + k]);      // wave-broadcast
      float4 a1 = *(const float4*)(&xs[n * NF + k + 4]);
      float a = acc[j];
      a = fmaf(a0.x, wv[0], a); a = fmaf(a0.y, wv[1], a);
      a = fmaf(a0.z, wv[2], a); a = fmaf(a0.w, wv[3], a);
      a = fmaf(a1.x, wv[4], a); a = fmaf(a1.y, wv[5], a);
      a = fmaf(a1.z, wv[6], a); a = fmaf(a1.w, wv[7], a);
      acc[j] = a;
    }
  }
  const size_t nb = (size_t)blockIdx.x * 16 + (size_t)g * 4;
#pragma unroll
  for (int j = 0; j < 4; ++j) h[(nb + j) * ND + d] = acc[j];
}

// One wave per edge: acc[t][lane] += h[s][lane] * dis[s]*w*dis[t]
__global__ __launch_bounds__(256) void scatter_kernel(
    const int* __restrict__ src, const int* __restrict__ dst,
    const float* __restrict__ ew, const float* __restrict__ dis,
    const float* __restrict__ h, float* __restrict__ acc) {
  const int lane = threadIdx.x & 63;
  const int wid = (blockIdx.x * 256 + threadIdx.x) >> 6;
  const int nw = (gridDim.x * 256) >> 6;
  for (int e = wid; e < NE; e += nw) {
    const int s = src[e];            // wave-uniform scalar loads
    const int t = dst[e];
    const float norm = dis[s] * ew[e] * dis[t];
    atomicAdd(&acc[t * ND + lane], h[s * ND + lane] * norm);
  }
}

// y = relu(acc + h*dis^2 (self-loop) + b1); out = y @ Weff2 + b2 (fp32 store)
__global__ __launch_bounds__(256) void epilogue_kernel(
    const float* __restrict__ acc, const float* __restrict__ h,
    const float* __restrict__ dis, const float* __restrict__ b1,
    const float* __restrict__ w2, const float* __restrict__ b2,
    float* __restrict__ out) {
  const int lane = threadIdx.x & 63;
  const int node = (blockIdx.x * 256 + threadIdx.x) >> 6;
  if (node >= NN) return;
  const float di = dis[node];
  float v = acc[node * ND + lane] + h[node * ND + lane] * di * di + b1[lane];
  v = fmaxf(v, 0.0f);
  float res = 0.0f;
#pragma unroll
  for (int c = 0; c < NC; ++c) {
    float p = v * w2[lane * NC + c];
#pragma unroll
    for (int off = 32; off > 0; off >>= 1) p += __shfl_xor(p, off, 64);
    if (lane == c) res = p + b2[c];
  }
  if (lane < NC) out[node * NC + lane] = res;
}

extern "C" void kernel_launch(void* const* d_in, const int* in_sizes, int n_in,
                              void* d_out, int out_size, void* d_ws, size_t ws_size,
                              hipStream_t stream) {
  const float* x  = (const float*)d_in[0];
  const int*   ei = (const int*)d_in[1];   // (2, NE) row-major int32
  const float* ew = (const float*)d_in[2];
  const float* W1 = (const float*)d_in[3];
  const float* M1 = (const float*)d_in[4];
  const float* b1 = (const float*)d_in[5];
  const float* W2 = (const float*)d_in[6];
  const float* M2 = (const float*)d_in[7];
  const float* b2 = (const float*)d_in[8];
  float* out = (float*)d_out;
  float* ws = (float*)d_ws;
  const int* src = ei;
  const int* dst = ei + NE;

  prep_kernel<<<NN * ND / 256, 256, 0, stream>>>(W1, M1, W2, M2, ws);
  deg_kernel<<<NE / 256, 256, 0, stream>>>(dst, ew, ws + OFF_DEG);
  dis_kernel<<<(NN + 255) / 256, 256, 0, stream>>>(ws + OFF_DEG);
  gemm1_kernel<<<NN / 16, 256, 0, stream>>>(x, ws + OFF_W1, ws + OFF_H);
  scatter_kernel<<<8192, 256, 0, stream>>>(src, dst, ew, ws + OFF_DEG,
                                           ws + OFF_H, ws + OFF_ACC);
  epilogue_kernel<<<NN / 4, 256, 0, stream>>>(ws + OFF_ACC, ws + OFF_H,
                                              ws + OFF_DEG, b1, ws + OFF_W2, b2, out);
}

// Round 4
// 1049.181 us; speedup vs baseline: 1.2475x; 1.2475x over previous
//
#include <hip/hip_runtime.h>

#define NN 100000
#define NE 3200000
#define NF 512
#define ND 64
#define NC 10
#define NB 391            // ceil(NN/256) blocks for node-sized kernels

// workspace layout (4-byte elements)
#define OFF_H      0          // NN*ND  h = x @ (W1*M1)
#define OFF_DEG    6400000    // NN     weighted degree -> deg^-1/2 in place
#define OFF_W1     6500000    // NF*ND  Weff1
#define OFF_W2     6532768    // ND*NC  Weff2
#define OFF_CNT    6533408    // NN     int in-degree counts; reused as fill cursor
#define OFF_RP     6633408    // NN+1   int CSR rowptr
#define OFF_BSUM   6733409    // 512    int block sums for scan
#define OFF_COL    6733921    // NE     int CSR src indices
#define OFF_VAL    9933921    // NE     float CSR edge norms
// total = 13,133,921 * 4B = 52.5 MB

// deg=1 (self-loop), cnt=0, masked weights.
__global__ __launch_bounds__(256) void prep_kernel(
    const float* __restrict__ W1, const float* __restrict__ M1,
    const float* __restrict__ W2, const float* __restrict__ M2,
    float* __restrict__ ws) {
  const int i = blockIdx.x * 256 + threadIdx.x;   // grid = NB blocks
  if (i < NN) { ws[OFF_DEG + i] = 1.0f; ((int*)ws)[OFF_CNT + i] = 0; }
  if (i < NF * ND) ws[OFF_W1 + i] = W1[i] * M1[i];
  if (i < ND * NC) ws[OFF_W2 + i] = W2[i] * M2[i];
}

// weighted in-degree + integer in-degree histogram
__global__ __launch_bounds__(256) void deg_kernel(
    const int* __restrict__ dst, const float* __restrict__ ew,
    float* __restrict__ deg, int* __restrict__ cnt) {
  const int i = blockIdx.x * 256 + threadIdx.x;   // grid covers exactly NE
  const int t = dst[i];
  atomicAdd(&deg[t], ew[i]);
  atomicAdd(&cnt[t], 1);
}

// deg -> deg^{-1/2} in place (deg >= 1 from self-loop)
__global__ __launch_bounds__(256) void dis_kernel(float* __restrict__ deg) {
  const int i = blockIdx.x * 256 + threadIdx.x;
  if (i < NN) {
    const float d = deg[i];
    deg[i] = d > 0.0f ? 1.0f / sqrtf(d) : 0.0f;
  }
}

// per-block sums of cnt -> bsum
__global__ __launch_bounds__(256) void scan_partial(
    const int* __restrict__ cnt, int* __restrict__ bsum) {
  __shared__ int s[256];
  const int i = blockIdx.x * 256 + threadIdx.x;
  int v = (i < NN) ? cnt[i] : 0;
  s[threadIdx.x] = v; __syncthreads();
  for (int off = 128; off > 0; off >>= 1) {
    if (threadIdx.x < off) s[threadIdx.x] += s[threadIdx.x + off];
    __syncthreads();
  }
  if (threadIdx.x == 0) bsum[blockIdx.x] = s[0];
}

// exclusive scan of the NB block sums (single block, Hillis-Steele)
__global__ __launch_bounds__(512) void scan_bsum(int* __restrict__ bsum) {
  __shared__ int s[512];
  const int t = threadIdx.x;
  const int v = (t < NB) ? bsum[t] : 0;
  s[t] = v; __syncthreads();
  for (int off = 1; off < 512; off <<= 1) {
    const int a = (t >= off) ? s[t - off] : 0;
    __syncthreads();
    s[t] += a;
    __syncthreads();
  }
  if (t < NB) bsum[t] = s[t] - v;   // exclusive
}

// per-block exclusive scan + offset -> rowptr; zero cnt for reuse as cursor
__global__ __launch_bounds__(256) void scan_final(
    int* __restrict__ cnt, const int* __restrict__ bsum,
    int* __restrict__ rowptr) {
  __shared__ int s[256];
  const int i = blockIdx.x * 256 + threadIdx.x;
  const int v = (i < NN) ? cnt[i] : 0;
  s[threadIdx.x] = v; __syncthreads();
  for (int off = 1; off < 256; off <<= 1) {
    const int a = (threadIdx.x >= off) ? s[threadIdx.x - off] : 0;
    __syncthreads();
    s[threadIdx.x] += a;
    __syncthreads();
  }
  if (i < NN) {
    const int excl = s[threadIdx.x] - v + bsum[blockIdx.x];
    rowptr[i] = excl;
    cnt[i] = 0;
    if (i == NN - 1) rowptr[NN] = excl + v;   // == NE
  }
}

// counting-sort fill: col/val bucketed by dst
__global__ __launch_bounds__(256) void fill_kernel(
    const int* __restrict__ src, const int* __restrict__ dst,
    const float* __restrict__ ew, const float* __restrict__ dis,
    const int* __restrict__ rowptr, int* __restrict__ cursor,
    int* __restrict__ col, float* __restrict__ val) {
  const int e = blockIdx.x * 256 + threadIdx.x;   // grid covers exactly NE
  const int s = src[e];
  const int t = dst[e];
  const float norm = dis[s] * ew[e] * dis[t];
  const int pos = rowptr[t] + atomicAdd(&cursor[t], 1);
  col[pos] = s;
  val[pos] = norm;
}

// h[n][d] = sum_k x[n][k] * Weff1[k][d].  16 nodes/block staged in LDS.
__global__ __launch_bounds__(256) void gemm1_kernel(
    const float* __restrict__ x, const float* __restrict__ w,
    float* __restrict__ h) {
  __shared__ __align__(16) float xs[16 * NF];   // 32 KB
  const float4* xg = (const float4*)(x + (size_t)blockIdx.x * (16 * NF));
  float4* xl = (float4*)xs;
#pragma unroll
  for (int i = 0; i < 8; ++i) xl[threadIdx.x + 256 * i] = xg[threadIdx.x + 256 * i];
  __syncthreads();
  const int d = threadIdx.x & 63;
  const int g = threadIdx.x >> 6;   // 0..3
  float acc[4];
#pragma unroll
  for (int j = 0; j < 4; ++j) acc[j] = 0.0f;
  for (int k = 0; k < NF; k += 8) {
    float wv[8];
#pragma unroll
    for (int kk = 0; kk < 8; ++kk) wv[kk] = w[(k + kk) * ND + d];  // coalesced
#pragma unroll
    for (int j = 0; j < 4; ++j) {
      const int n = g * 4 + j;
      float4 a0 = *(const float4*)(&xs[n * NF + k]);
      float4 a1 = *(const float4*)(&xs[n * NF + k + 4]);
      float a = acc[j];
      a = fmaf(a0.x, wv[0], a); a = fmaf(a0.y, wv[1], a);
      a = fmaf(a0.z, wv[2], a); a = fmaf(a0.w, wv[3], a);
      a = fmaf(a1.x, wv[4], a); a = fmaf(a1.y, wv[5], a);
      a = fmaf(a1.z, wv[6], a); a = fmaf(a1.w, wv[7], a);
      acc[j] = a;
    }
  }
  const size_t nb = (size_t)blockIdx.x * 16 + (size_t)g * 4;
#pragma unroll
  for (int j = 0; j < 4; ++j) h[(nb + j) * ND + d] = acc[j];
}

// One wave per dst node: sum = Σ_e h[col[e]][lane]*val[e]; fused self-loop,
// bias, ReLU, and 64x10 classifier. No acc array, no atomics.
__global__ __launch_bounds__(256) void gather_kernel(
    const int* __restrict__ rowptr, const int* __restrict__ col,
    const float* __restrict__ val, const float* __restrict__ h,
    const float* __restrict__ dis, const float* __restrict__ b1,
    const float* __restrict__ w2, const float* __restrict__ b2,
    float* __restrict__ out) {
  const int lane = threadIdx.x & 63;
  const int n = (blockIdx.x * 256 + threadIdx.x) >> 6;
  if (n >= NN) return;
  const int beg = rowptr[n];
  const int end = rowptr[n + 1];
  float s0 = 0.0f, s1 = 0.0f, s2 = 0.0f, s3 = 0.0f;
  for (int base = beg; base < end; base += 64) {
    int c = 0; float v = 0.0f;
    const int e = base + lane;
    if (e < end) { c = col[e]; v = val[e]; }   // coalesced batch load
    const int m = min(64, end - base);
    int j = 0;
    for (; j + 4 <= m; j += 4) {               // 4 independent gather chains
      const int   c0 = __shfl(c, j, 64),     c1 = __shfl(c, j + 1, 64);
      const int   c2 = __shfl(c, j + 2, 64), c3 = __shfl(c, j + 3, 64);
      const float v0 = __shfl(v, j, 64),     v1 = __shfl(v, j + 1, 64);
      const float v2 = __shfl(v, j + 2, 64), v3 = __shfl(v, j + 3, 64);
      const float h0 = h[(size_t)c0 * ND + lane];
      const float h1 = h[(size_t)c1 * ND + lane];
      const float h2 = h[(size_t)c2 * ND + lane];
      const float h3 = h[(size_t)c3 * ND + lane];
      s0 = fmaf(h0, v0, s0); s1 = fmaf(h1, v1, s1);
      s2 = fmaf(h2, v2, s2); s3 = fmaf(h3, v3, s3);
    }
    for (; j < m; ++j) {
      const int cc = __shfl(c, j, 64);
      const float vv = __shfl(v, j, 64);
      s0 = fmaf(h[(size_t)cc * ND + lane], vv, s0);
    }
  }
  const float di = dis[n];
  float vv = (s0 + s1) + (s2 + s3) + h[(size_t)n * ND + lane] * di * di + b1[lane];
  vv = fmaxf(vv, 0.0f);
  float res = 0.0f;
#pragma unroll
  for (int cix = 0; cix < NC; ++cix) {
    float p = vv * w2[lane * NC + cix];
#pragma unroll
    for (int off = 32; off > 0; off >>= 1) p += __shfl_xor(p, off, 64);
    if (lane == cix) res = p + b2[cix];
  }
  if (lane < NC) out[n * NC + lane] = res;
}

extern "C" void kernel_launch(void* const* d_in, const int* in_sizes, int n_in,
                              void* d_out, int out_size, void* d_ws, size_t ws_size,
                              hipStream_t stream) {
  const float* x  = (const float*)d_in[0];
  const int*   ei = (const int*)d_in[1];   // (2, NE) row-major int32
  const float* ew = (const float*)d_in[2];
  const float* W1 = (const float*)d_in[3];
  const float* M1 = (const float*)d_in[4];
  const float* b1 = (const float*)d_in[5];
  const float* W2 = (const float*)d_in[6];
  const float* M2 = (const float*)d_in[7];
  const float* b2 = (const float*)d_in[8];
  float* out = (float*)d_out;
  float* ws  = (float*)d_ws;
  int*   wsi = (int*)d_ws;
  const int* src = ei;
  const int* dst = ei + NE;

  prep_kernel<<<NB, 256, 0, stream>>>(W1, M1, W2, M2, ws);
  deg_kernel<<<NE / 256, 256, 0, stream>>>(dst, ew, ws + OFF_DEG, wsi + OFF_CNT);
  dis_kernel<<<NB, 256, 0, stream>>>(ws + OFF_DEG);
  scan_partial<<<NB, 256, 0, stream>>>(wsi + OFF_CNT, wsi + OFF_BSUM);
  scan_bsum<<<1, 512, 0, stream>>>(wsi + OFF_BSUM);
  scan_final<<<NB, 256, 0, stream>>>(wsi + OFF_CNT, wsi + OFF_BSUM, wsi + OFF_RP);
  fill_kernel<<<NE / 256, 256, 0, stream>>>(src, dst, ew, ws + OFF_DEG,
                                            wsi + OFF_RP, wsi + OFF_CNT,
                                            wsi + OFF_COL, ws + OFF_VAL);
  gemm1_kernel<<<NN / 16, 256, 0, stream>>>(x, ws + OFF_W1, ws + OFF_H);
  gather_kernel<<<NN / 4, 256, 0, stream>>>(wsi + OFF_RP, wsi + OFF_COL,
                                            ws + OFF_VAL, ws + OFF_H,
                                            ws + OFF_DEG, b1, ws + OFF_W2, b2, out);
}

// Round 5
// 799.403 us; speedup vs baseline: 1.6373x; 1.3125x over previous
//
#include <hip/hip_runtime.h>

#define NN 100000
#define NE 3200000
#define NF 512
#define ND 64
#define NC 10
#define NB 391            // ceil(NN/256)

// workspace layout (4-byte elements)
#define OFF_H      0          // NN*ND  h = x @ (W1*M1); rank[] aliases first NE
#define OFF_RANK   0          //        (consumed by fill before gemm1 writes h)
#define OFF_DIS    6400000    // NN     deg^-1/2
#define OFF_W1     6500000    // NF*ND  Weff1
#define OFF_W2     6532768    // ND*NC  Weff2
#define OFF_CNT    6533408    // NN     int in-degree histogram
#define OFF_RP     6633408    // NN+1   int CSR rowptr
#define OFF_BSUM   6733409    // 512    int block sums for scan
#define OFF_EDGE   6733922    // NE int2 {src, bits(w)}  (8B-aligned: even)
// total = 13,133,922 * 4B = 52.5 MB

// cnt=0, masked weights
__global__ __launch_bounds__(256) void prep_kernel(
    const float* __restrict__ W1, const float* __restrict__ M1,
    const float* __restrict__ W2, const float* __restrict__ M2,
    float* __restrict__ ws) {
  const int i = blockIdx.x * 256 + threadIdx.x;   // grid = NB
  if (i < NN) ((int*)ws)[OFF_CNT + i] = 0;
  if (i < NF * ND) ws[OFF_W1 + i] = W1[i] * M1[i];
  if (i < ND * NC) ws[OFF_W2 + i] = W2[i] * M2[i];
}

// the ONLY atomic pass: histogram + record each edge's intra-bucket rank
__global__ __launch_bounds__(256) void hist_kernel(
    const int* __restrict__ dst, int* __restrict__ cnt,
    int* __restrict__ rank) {
  const int e = blockIdx.x * 256 + threadIdx.x;   // grid covers exactly NE
  rank[e] = atomicAdd(&cnt[dst[e]], 1);
}

// per-block sums of cnt -> bsum
__global__ __launch_bounds__(256) void scan_partial(
    const int* __restrict__ cnt, int* __restrict__ bsum) {
  __shared__ int s[256];
  const int i = blockIdx.x * 256 + threadIdx.x;
  int v = (i < NN) ? cnt[i] : 0;
  s[threadIdx.x] = v; __syncthreads();
  for (int off = 128; off > 0; off >>= 1) {
    if (threadIdx.x < off) s[threadIdx.x] += s[threadIdx.x + off];
    __syncthreads();
  }
  if (threadIdx.x == 0) bsum[blockIdx.x] = s[0];
}

// exclusive scan of the NB block sums (single block)
__global__ __launch_bounds__(512) void scan_bsum(int* __restrict__ bsum) {
  __shared__ int s[512];
  const int t = threadIdx.x;
  const int v = (t < NB) ? bsum[t] : 0;
  s[t] = v; __syncthreads();
  for (int off = 1; off < 512; off <<= 1) {
    const int a = (t >= off) ? s[t - off] : 0;
    __syncthreads();
    s[t] += a;
    __syncthreads();
  }
  if (t < NB) bsum[t] = s[t] - v;   // exclusive
}

// per-block exclusive scan + offset -> rowptr
__global__ __launch_bounds__(256) void scan_final(
    const int* __restrict__ cnt, const int* __restrict__ bsum,
    int* __restrict__ rowptr) {
  __shared__ int s[256];
  const int i = blockIdx.x * 256 + threadIdx.x;
  const int v = (i < NN) ? cnt[i] : 0;
  s[threadIdx.x] = v; __syncthreads();
  for (int off = 1; off < 256; off <<= 1) {
    const int a = (threadIdx.x >= off) ? s[threadIdx.x - off] : 0;
    __syncthreads();
    s[threadIdx.x] += a;
    __syncthreads();
  }
  if (i < NN) {
    const int excl = s[threadIdx.x] - v + bsum[blockIdx.x];
    rowptr[i] = excl;
    if (i == NN - 1) rowptr[NN] = excl + v;   // == NE
  }
}

// atomic-free counting-sort fill: edge[rowptr[dst]+rank] = {src, w}
__global__ __launch_bounds__(256) void fill_kernel(
    const int* __restrict__ src, const int* __restrict__ dst,
    const float* __restrict__ ew, const int* __restrict__ rank,
    const int* __restrict__ rowptr, int2* __restrict__ edge) {
  const int e = blockIdx.x * 256 + threadIdx.x;   // grid covers exactly NE
  const int pos = rowptr[dst[e]] + rank[e];
  edge[pos] = make_int2(src[e], __float_as_int(ew[e]));
}

// deg[n] = 1 + row-sum of w; dis = rsqrt(deg). Thread per node.
__global__ __launch_bounds__(256) void degdis_kernel(
    const int* __restrict__ rowptr, const int2* __restrict__ edge,
    float* __restrict__ dis) {
  const int n = blockIdx.x * 256 + threadIdx.x;
  if (n >= NN) return;
  const int beg = rowptr[n], end = rowptr[n + 1];
  float s = 1.0f;                         // self-loop weight
  for (int e = beg; e < end; ++e) s += __int_as_float(edge[e].y);
  dis[n] = rsqrtf(s);
}

// h[n][d] = sum_k x[n][k] * Weff1[k][d].  16 nodes/block staged in LDS.
__global__ __launch_bounds__(256) void gemm1_kernel(
    const float* __restrict__ x, const float* __restrict__ w,
    float* __restrict__ h) {
  __shared__ __align__(16) float xs[16 * NF];   // 32 KB
  const float4* xg = (const float4*)(x + (size_t)blockIdx.x * (16 * NF));
  float4* xl = (float4*)xs;
#pragma unroll
  for (int i = 0; i < 8; ++i) xl[threadIdx.x + 256 * i] = xg[threadIdx.x + 256 * i];
  __syncthreads();
  const int d = threadIdx.x & 63;
  const int g = threadIdx.x >> 6;   // 0..3
  float acc[4];
#pragma unroll
  for (int j = 0; j < 4; ++j) acc[j] = 0.0f;
  for (int k = 0; k < NF; k += 8) {
    float wv[8];
#pragma unroll
    for (int kk = 0; kk < 8; ++kk) wv[kk] = w[(k + kk) * ND + d];  // coalesced
#pragma unroll
    for (int j = 0; j < 4; ++j) {
      const int n = g * 4 + j;
      float4 a0 = *(const float4*)(&xs[n * NF + k]);
      float4 a1 = *(const float4*)(&xs[n * NF + k + 4]);
      float a = acc[j];
      a = fmaf(a0.x, wv[0], a); a = fmaf(a0.y, wv[1], a);
      a = fmaf(a0.z, wv[2], a); a = fmaf(a0.w, wv[3], a);
      a = fmaf(a1.x, wv[4], a); a = fmaf(a1.y, wv[5], a);
      a = fmaf(a1.z, wv[6], a); a = fmaf(a1.w, wv[7], a);
      acc[j] = a;
    }
  }
  const size_t nb = (size_t)blockIdx.x * 16 + (size_t)g * 4;
#pragma unroll
  for (int j = 0; j < 4; ++j) h[(nb + j) * ND + d] = acc[j];
}

// One wave per dst node.  Row result = dis[n] * Σ_e (w·dis[src])·h[src][lane],
// then fused self-loop, bias, ReLU and 64x10 classifier.
__global__ __launch_bounds__(256) void gather_kernel(
    const int* __restrict__ rowptr, const int2* __restrict__ edge,
    const float* __restrict__ h, const float* __restrict__ dis,
    const float* __restrict__ b1, const float* __restrict__ w2,
    const float* __restrict__ b2, float* __restrict__ out) {
  const int lane = threadIdx.x & 63;
  const int n = (blockIdx.x * 256 + threadIdx.x) >> 6;
  if (n >= NN) return;
  const int beg = rowptr[n];
  const int end = rowptr[n + 1];
  float s0 = 0.0f, s1 = 0.0f, s2 = 0.0f, s3 = 0.0f;
  for (int base = beg; base < end; base += 64) {
    int c = 0; float p = 0.0f;
    const int e = base + lane;
    if (e < end) {                      // coalesced 8B/lane batch load
      const int2 ed = edge[e];
      c = ed.x;
      p = __int_as_float(ed.y) * dis[c];   // w * dis[src]  (L2-resident gather)
    }
    const int m = min(64, end - base);
    int j = 0;
    for (; j + 4 <= m; j += 4) {        // 4 independent gather chains
      const int   c0 = __shfl(c, j, 64),     c1 = __shfl(c, j + 1, 64);
      const int   c2 = __shfl(c, j + 2, 64), c3 = __shfl(c, j + 3, 64);
      const float p0 = __shfl(p, j, 64),     p1 = __shfl(p, j + 1, 64);
      const float p2 = __shfl(p, j + 2, 64), p3 = __shfl(p, j + 3, 64);
      const float h0 = h[(size_t)c0 * ND + lane];
      const float h1 = h[(size_t)c1 * ND + lane];
      const float h2 = h[(size_t)c2 * ND + lane];
      const float h3 = h[(size_t)c3 * ND + lane];
      s0 = fmaf(h0, p0, s0); s1 = fmaf(h1, p1, s1);
      s2 = fmaf(h2, p2, s2); s3 = fmaf(h3, p3, s3);
    }
    for (; j < m; ++j) {
      const int cc = __shfl(c, j, 64);
      const float pp = __shfl(p, j, 64);
      s0 = fmaf(h[(size_t)cc * ND + lane], pp, s0);
    }
  }
  const float dn = dis[n];
  const float hn = h[(size_t)n * ND + lane];
  float vv = fmaf(((s0 + s1) + (s2 + s3)) + hn * dn, dn, b1[lane]);
  vv = fmaxf(vv, 0.0f);
  float res = 0.0f;
#pragma unroll
  for (int cix = 0; cix < NC; ++cix) {
    float q = vv * w2[lane * NC + cix];
#pragma unroll
    for (int off = 32; off > 0; off >>= 1) q += __shfl_xor(q, off, 64);
    if (lane == cix) res = q + b2[cix];
  }
  if (lane < NC) out[n * NC + lane] = res;
}

extern "C" void kernel_launch(void* const* d_in, const int* in_sizes, int n_in,
                              void* d_out, int out_size, void* d_ws, size_t ws_size,
                              hipStream_t stream) {
  const float* x  = (const float*)d_in[0];
  const int*   ei = (const int*)d_in[1];   // (2, NE) row-major int32
  const float* ew = (const float*)d_in[2];
  const float* W1 = (const float*)d_in[3];
  const float* M1 = (const float*)d_in[4];
  const float* b1 = (const float*)d_in[5];
  const float* W2 = (const float*)d_in[6];
  const float* M2 = (const float*)d_in[7];
  const float* b2 = (const float*)d_in[8];
  float* out = (float*)d_out;
  float* ws  = (float*)d_ws;
  int*   wsi = (int*)d_ws;
  const int* src = ei;
  const int* dst = ei + NE;
  int2* edge = (int2*)(wsi + OFF_EDGE);

  prep_kernel<<<NB, 256, 0, stream>>>(W1, M1, W2, M2, ws);
  hist_kernel<<<NE / 256, 256, 0, stream>>>(dst, wsi + OFF_CNT, wsi + OFF_RANK);
  scan_partial<<<NB, 256, 0, stream>>>(wsi + OFF_CNT, wsi + OFF_BSUM);
  scan_bsum<<<1, 512, 0, stream>>>(wsi + OFF_BSUM);
  scan_final<<<NB, 256, 0, stream>>>(wsi + OFF_CNT, wsi + OFF_BSUM, wsi + OFF_RP);
  fill_kernel<<<NE / 256, 256, 0, stream>>>(src, dst, ew, wsi + OFF_RANK,
                                            wsi + OFF_RP, edge);
  degdis_kernel<<<NB, 256, 0, stream>>>(wsi + OFF_RP, edge, ws + OFF_DIS);
  gemm1_kernel<<<NN / 16, 256, 0, stream>>>(x, ws + OFF_W1, ws + OFF_H);
  gather_kernel<<<NN / 4, 256, 0, stream>>>(wsi + OFF_RP, edge, ws + OFF_H,
                                            ws + OFF_DIS, b1, ws + OFF_W2, b2, out);
}